// Round 1
// baseline (615.011 us; speedup 1.0000x reference)
//
#include <hip/hip_runtime.h>

#define B_SZ 64
#define T_LEN 2048
#define NIN 257
#define HID 32
#define G4 128
#define NOUT 10

#define TBT 128         // rows per xproj tile
#define PAD 34
#define CH 8
#define NSCAN 64
#define NTILE 1024      // 16 t-tiles * 64 batches
#define TPB 16          // t-tiles per batch

typedef int v2i __attribute__((ext_vector_type(2)));
typedef unsigned long long u64;

__device__ __forceinline__ float fsig(float x) {
  return __builtin_amdgcn_rcpf(1.f + __builtin_amdgcn_exp2f(-1.44269504089f * x));
}

// acc.x += w.x * h2.lo ; acc.y += w.y * h2.hi   (standard packed, no op_sel)
__device__ __forceinline__ void pkfma2(float2& acc, float2 w, u64 h2) {
  asm("v_pk_fma_f32 %0, %1, %2, %0" : "+v"(acc) : "v"(w), "s"(h2));
}

__device__ __forceinline__ float2 pkadd(float2 a, float2 b) {
  float2 d;
  asm("v_pk_add_f32 %0, %1, %2" : "=v"(d) : "v"(a), "v"(b));
  return d;
}

// ---- GEMM tile body: writes xproj rows [bt0, bt0+128) ----
__device__ __forceinline__ void gemm_tile(
    const float* __restrict__ A, const float* __restrict__ W,
    const float* __restrict__ b_ih, const float* __restrict__ b_hh,
    float* __restrict__ C, int bt0, float* sA, float* sB)
{
  const int tid = threadIdx.x;
  const int gt = tid & 15;
  const int btt = tid >> 4;
  float acc[8][8];
#pragma unroll
  for (int i = 0; i < 8; ++i)
#pragma unroll
    for (int j = 0; j < 8; ++j) acc[i][j] = 0.f;

  for (int kc = 0; kc < 8; ++kc) {
    const int k0 = kc * 32;
    __syncthreads();
#pragma unroll
    for (int i = 0; i < 16; ++i) {
      int s = i * 256 + tid;
      int r = s >> 5, cc = s & 31;
      sA[r * PAD + cc] = A[(size_t)(bt0 + r) * NIN + k0 + cc];
      sB[r * PAD + cc] = W[(size_t)r * NIN + k0 + cc];
    }
    __syncthreads();
#pragma unroll
    for (int k2 = 0; k2 < 16; ++k2) {
      float2 a2[8], b2[8];
#pragma unroll
      for (int i = 0; i < 8; ++i)
        a2[i] = *(const float2*)&sA[(btt + 16 * i) * PAD + 2 * k2];
#pragma unroll
      for (int j = 0; j < 8; ++j)
        b2[j] = *(const float2*)&sB[(gt + 16 * j) * PAD + 2 * k2];
#pragma unroll
      for (int i = 0; i < 8; ++i)
#pragma unroll
        for (int j = 0; j < 8; ++j) {
          acc[i][j] = fmaf(a2[i].x, b2[j].x, acc[i][j]);
          acc[i][j] = fmaf(a2[i].y, b2[j].y, acc[i][j]);
        }
    }
  }
  { // k = 256 tail
    float a[8], bb[8];
#pragma unroll
    for (int i = 0; i < 8; ++i) a[i] = A[(size_t)(bt0 + btt + 16 * i) * NIN + 256];
#pragma unroll
    for (int j = 0; j < 8; ++j) bb[j] = W[(size_t)(gt + 16 * j) * NIN + 256];
#pragma unroll
    for (int i = 0; i < 8; ++i)
#pragma unroll
      for (int j = 0; j < 8; ++j) acc[i][j] += a[i] * bb[j];
  }
  float bias[8];
#pragma unroll
  for (int j = 0; j < 8; ++j) bias[j] = b_ih[gt + 16 * j] + b_hh[gt + 16 * j];
#pragma unroll
  for (int i = 0; i < 8; ++i) {
    size_t row = (size_t)(bt0 + btt + 16 * i) * G4;
#pragma unroll
    for (int j = 0; j < 8; ++j) C[row + gt + 16 * j] = acc[i][j] + bias[j];
  }
}

// ---- standalone GEMM: 1024 blocks = 4 blocks/CU, 4 waves/SIMD ----
__global__ __launch_bounds__(256) void xproj_gemm(
    const float* __restrict__ A, const float* __restrict__ W,
    const float* __restrict__ b_ih, const float* __restrict__ b_hh,
    float* __restrict__ C)
{
  __shared__ float sA[TBT * PAD];
  __shared__ float sB[G4 * PAD];
  const int idx = blockIdx.x;
  const int ti = idx >> 6, bb = idx & 63;
  gemm_tile(A, W, b_ih, b_hh, C, bb * T_LEN + ti * TBT, sA, sB);
}

// ---- scan kernel: one wave per batch element (launched grid=64, 64 thr) ----
__global__ __launch_bounds__(256) void fused(
    const float* __restrict__ A,      // specs (unused here, kept for signature)
    const float* __restrict__ W,      // W_ih (unused)
    const float* __restrict__ b_ih,
    const float* __restrict__ b_hh,
    const float* __restrict__ W_hh,
    const float* __restrict__ W_out,
    const float* __restrict__ b_out,
    float* __restrict__ out,
    float* __restrict__ xproj,
    int* __restrict__ flags,
    int nowait)
{
  const int bid = blockIdx.x;
  if (threadIdx.x >= 64) return;
  __builtin_amdgcn_s_setprio(3);
  const int b = bid;
  const int l = threadIdx.x;

  // packed K-pair weights: wA[j] = (W_hh[l][2j], W_hh[l][2j+1]); wB row l+64
  float2 wA[16], wB[16];
#pragma unroll
  for (int j = 0; j < 16; j += 2) {
    float4 v0 = *(const float4*)&W_hh[l * HID + 2 * j];
    wA[j]     = make_float2(v0.x, v0.y);
    wA[j + 1] = make_float2(v0.z, v0.w);
    float4 v1 = *(const float4*)&W_hh[(l + 64) * HID + 2 * j];
    wB[j]     = make_float2(v1.x, v1.y);
    wB[j + 1] = make_float2(v1.z, v1.w);
  }
  const float sBc = (l < HID) ? 2.f : 1.f;
  const float mBc = (l < HID) ? 2.f : 1.f;
  const float aBc = (l < HID) ? -1.f : 0.f;

  float c = 0.f, h = 0.f;
  u64 hp[16];
#pragma unroll
  for (int k = 0; k < 16; ++k) hp[k] = 0ull;

  const float* xb = xproj + (size_t)b * T_LEN * G4;

  auto step = [&](float xa, float xg) {
    // 4 independent chains of depth 4 per gate (was 2 chains of depth 8)
    float2 aA[4], aB[4];
    aA[0] = make_float2(xa, 0.f);
    aB[0] = make_float2(xg, 0.f);
#pragma unroll
    for (int q = 1; q < 4; ++q) {
      aA[q] = make_float2(0.f, 0.f);
      aB[q] = make_float2(0.f, 0.f);
    }
#pragma unroll
    for (int j = 0; j < 16; j += 4) {
#pragma unroll
      for (int q = 0; q < 4; ++q) {
        pkfma2(aA[q], wA[j + q], hp[j + q]);
        pkfma2(aB[q], wB[j + q], hp[j + q]);
      }
    }
    float2 tA = pkadd(pkadd(aA[0], aA[1]), pkadd(aA[2], aA[3]));
    float2 tB = pkadd(pkadd(aB[0], aB[1]), pkadd(aB[2], aB[3]));
    float accA = tA.x + tA.y;                  // i (l<32) / f (l>=32)
    float accB = tB.x + tB.y;                  // g (l<32) / o (l>=32)
    float actA = fsig(accA);
    float actB = mBc * fsig(accB * sBc) + aBc; // tanh g (l<32) / o (l>=32)
    float prod = actA * actB;                  // lanes<32: i*g
    // measured semantics: swap(vdst=0, src=prod) -> dst_new[32+k] = prod[k]
    v2i sw = __builtin_amdgcn_permlane32_swap(0, __float_as_int(prod), false, false);
    float pr = __int_as_float(sw[0]);
    c = fmaf(actA, c, pr);                     // lanes>=32: c = f*c + i*g
    float th = 2.f * fsig(c + c) - 1.f;        // tanh(c)
    h = actB * th;                             // lanes>=32: h = o*tanh(c)
#pragma unroll
    for (int k = 0; k < 16; ++k) {
      unsigned lo = (unsigned)__builtin_amdgcn_readlane(__float_as_int(h), 32 + 2 * k);
      unsigned hi = (unsigned)__builtin_amdgcn_readlane(__float_as_int(h), 33 + 2 * k);
      hp[k] = (u64)lo | ((u64)hi << 32);
    }
  };

  for (int ti = 0; ti < TPB; ++ti) {
    if (!nowait) {
      while (__hip_atomic_load(&flags[ti * 64 + b], __ATOMIC_ACQUIRE,
                               __HIP_MEMORY_SCOPE_AGENT) == 0)
        __builtin_amdgcn_s_sleep(2);
    }
    const float* xt = xb + (size_t)ti * TBT * G4;
    float A0[CH], B0[CH], A1[CH], B1[CH];
#pragma unroll
    for (int i = 0; i < CH; ++i) {
      A0[i] = xt[i * G4 + l];
      B0[i] = xt[i * G4 + 64 + l];
    }
    for (int ch = 0; ch < TBT / CH; ch += 2) {
      const float* s1 = xt + (size_t)(ch + 1) * CH * G4;
#pragma unroll
      for (int i = 0; i < CH; ++i) {
        A1[i] = s1[i * G4 + l];
        B1[i] = s1[i * G4 + 64 + l];
      }
#pragma unroll
      for (int i = 0; i < CH; ++i) step(A0[i], B0[i]);
      if (ch + 2 < TBT / CH) {
        const float* s2 = xt + (size_t)(ch + 2) * CH * G4;
#pragma unroll
        for (int i = 0; i < CH; ++i) {
          A0[i] = s2[i * G4 + l];
          B0[i] = s2[i * G4 + 64 + l];
        }
      }
#pragma unroll
      for (int i = 0; i < CH; ++i) step(A1[i], B1[i]);
    }
  }

  // head: logits = relu(h) @ W_out.T + b_out ; log_softmax  (shuffle-only)
  float hf[HID];
#pragma unroll
  for (int k = 0; k < HID; ++k)
    hf[k] = __int_as_float(__builtin_amdgcn_readlane(__float_as_int(h), 32 + k));
  float logit = 0.f;
  if (l < NOUT) {
    logit = b_out[l];
#pragma unroll
    for (int j = 0; j < HID; ++j) logit += fmaxf(hf[j], 0.f) * W_out[l * HID + j];
  }
  float m = -1e30f;
#pragma unroll
  for (int n = 0; n < NOUT; ++n) m = fmaxf(m, __shfl(logit, n));
  float s = 0.f;
#pragma unroll
  for (int n = 0; n < NOUT; ++n)
    s += __builtin_amdgcn_exp2f(1.44269504089f * (__shfl(logit, n) - m));
  if (l < NOUT)
    out[b * NOUT + l] = logit - m - 0.69314718056f * __builtin_amdgcn_logf(s);
}

extern "C" void kernel_launch(void* const* d_in, const int* in_sizes, int n_in,
                              void* d_out, int out_size, void* d_ws, size_t ws_size,
                              hipStream_t stream) {
  const float* specs = (const float*)d_in[0];
  const float* W_ih  = (const float*)d_in[1];
  const float* W_hh  = (const float*)d_in[2];
  const float* b_ih  = (const float*)d_in[3];
  const float* b_hh  = (const float*)d_in[4];
  const float* W_out = (const float*)d_in[5];
  const float* b_out = (const float*)d_in[6];
  float* outp  = (float*)d_out;
  float* xproj = (float*)d_ws;                       // 64 MB

  // Serial decomposition: (1) dense GEMM at 4 blocks/CU, (2) scan-only at
  // 64 blocks x 64 threads with the rest of the chip idle (clock headroom).
  // Kernel-boundary release/acquire makes xproj visible to the scan.
  xproj_gemm<<<NTILE, 256, 0, stream>>>(specs, W_ih, b_ih, b_hh, xproj);
  fused<<<NSCAN, 64, 0, stream>>>(specs, W_ih, b_ih, b_hh, W_hh,
                                  W_out, b_out, outp, xproj,
                                  (int*)xproj /*unused*/, 1 /*nowait*/);
}

// Round 2
// 571.761 us; speedup vs baseline: 1.0756x; 1.0756x over previous
//
#include <hip/hip_runtime.h>

#define B_SZ 64
#define T_LEN 2048
#define NIN 257
#define HID 32
#define G4 128
#define NOUT 10

#define TBT 128         // rows per xproj tile
#define PAD 34
#define CH 8
#define NSCAN 64
#define NGEMMP 128      // 64 scan + 128 gemm = 192 blocks (<=1 per CU, lower power)
#define NTILE 1024      // 16 t-tiles * 64 batches
#define TPB 16          // t-tiles per batch

typedef int v2i __attribute__((ext_vector_type(2)));
typedef unsigned long long u64;

// acc.x += w.x * h2.lo ; acc.y += w.y * h2.hi   (standard packed, no op_sel)
__device__ __forceinline__ void pkfma2(float2& acc, float2 w, u64 h2) {
  asm("v_pk_fma_f32 %0, %1, %2, %0" : "+v"(acc) : "v"(w), "s"(h2));
}

__device__ __forceinline__ float2 pkadd(float2 a, float2 b) {
  float2 d;
  asm("v_pk_add_f32 %0, %1, %2" : "=v"(d) : "v"(a), "v"(b));
  return d;
}

// ---- asm-pinned prefetch: one (xa,xg) dword pair per step, imm offsets ----
#define LDP(a0, b0, PB, OA, OB) \
  asm volatile("global_load_dword %0, %2, off offset:" OA "\n\t" \
               "global_load_dword %1, %2, off offset:" OB \
               : "=&v"(a0), "=&v"(b0) : "v"(PB))

#define LOAD_CHUNK(Aa, Bb, PB) do { \
  LDP(Aa[0], Bb[0], PB, "0",    "256");  \
  LDP(Aa[1], Bb[1], PB, "512",  "768");  \
  LDP(Aa[2], Bb[2], PB, "1024", "1280"); \
  LDP(Aa[3], Bb[3], PB, "1536", "1792"); \
  LDP(Aa[4], Bb[4], PB, "2048", "2304"); \
  LDP(Aa[5], Bb[5], PB, "2560", "2816"); \
  LDP(Aa[6], Bb[6], PB, "3072", "3328"); \
  LDP(Aa[7], Bb[7], PB, "3584", "3840"); \
} while (0)

// counted wait: previous chunk (16 loads) retired; next chunk stays in flight
#define WAIT16() do { asm volatile("s_waitcnt vmcnt(16)" ::: "memory"); \
                      __builtin_amdgcn_sched_barrier(0); } while (0)
#define WAIT0()  do { asm volatile("s_waitcnt vmcnt(0)" ::: "memory"); \
                      __builtin_amdgcn_sched_barrier(0); } while (0)

// ---- GEMM tile body: writes xproj rows [bt0, bt0+128) ----
__device__ __forceinline__ void gemm_tile(
    const float* __restrict__ A, const float* __restrict__ W,
    const float* __restrict__ b_ih, const float* __restrict__ b_hh,
    float* __restrict__ C, int bt0, float* sA, float* sB)
{
  const int tid = threadIdx.x;
  const int gt = tid & 15;
  const int btt = tid >> 4;
  float acc[8][8];
#pragma unroll
  for (int i = 0; i < 8; ++i)
#pragma unroll
    for (int j = 0; j < 8; ++j) acc[i][j] = 0.f;

  for (int kc = 0; kc < 8; ++kc) {
    const int k0 = kc * 32;
    __syncthreads();
#pragma unroll
    for (int i = 0; i < 16; ++i) {
      int s = i * 256 + tid;
      int r = s >> 5, cc = s & 31;
      sA[r * PAD + cc] = A[(size_t)(bt0 + r) * NIN + k0 + cc];
      sB[r * PAD + cc] = W[(size_t)r * NIN + k0 + cc];
    }
    __syncthreads();
#pragma unroll
    for (int k2 = 0; k2 < 16; ++k2) {
      float2 a2[8], b2[8];
#pragma unroll
      for (int i = 0; i < 8; ++i)
        a2[i] = *(const float2*)&sA[(btt + 16 * i) * PAD + 2 * k2];
#pragma unroll
      for (int j = 0; j < 8; ++j)
        b2[j] = *(const float2*)&sB[(gt + 16 * j) * PAD + 2 * k2];
#pragma unroll
      for (int i = 0; i < 8; ++i)
#pragma unroll
        for (int j = 0; j < 8; ++j) {
          acc[i][j] = fmaf(a2[i].x, b2[j].x, acc[i][j]);
          acc[i][j] = fmaf(a2[i].y, b2[j].y, acc[i][j]);
        }
    }
  }
  { // k = 256 tail
    float a[8], bb[8];
#pragma unroll
    for (int i = 0; i < 8; ++i) a[i] = A[(size_t)(bt0 + btt + 16 * i) * NIN + 256];
#pragma unroll
    for (int j = 0; j < 8; ++j) bb[j] = W[(size_t)(gt + 16 * j) * NIN + 256];
#pragma unroll
    for (int i = 0; i < 8; ++i)
#pragma unroll
      for (int j = 0; j < 8; ++j) acc[i][j] += a[i] * bb[j];
  }
  float bias[8];
#pragma unroll
  for (int j = 0; j < 8; ++j) bias[j] = b_ih[gt + 16 * j] + b_hh[gt + 16 * j];
#pragma unroll
  for (int i = 0; i < 8; ++i) {
    size_t row = (size_t)(bt0 + btt + 16 * i) * G4;
#pragma unroll
    for (int j = 0; j < 8; ++j) C[row + gt + 16 * j] = acc[i][j] + bias[j];
  }
}

// ---- Fused kernel: blocks [0,64) scan, [64,192) persistent GEMM ----
__global__ __launch_bounds__(256) void fused(
    const float* __restrict__ A,      // specs
    const float* __restrict__ W,      // W_ih
    const float* __restrict__ b_ih,
    const float* __restrict__ b_hh,
    const float* __restrict__ W_hh,
    const float* __restrict__ W_out,
    const float* __restrict__ b_out,
    float* __restrict__ out,
    float* __restrict__ xproj,
    int* __restrict__ flags,
    int nowait)
{
  __shared__ float sA[TBT * PAD];
  __shared__ float sB[G4 * PAD];
  const int bid = blockIdx.x;

  if (bid >= NSCAN) {
    // -------- producer: persistent GEMM, tile-major (ti*64 + b) --------
    const int p = bid - NSCAN;
    for (int idx = p; idx < NTILE; idx += NGEMMP) {
      const int ti = idx >> 6, bb = idx & 63;
      const int bt0 = bb * T_LEN + ti * TBT;
      gemm_tile(A, W, b_ih, b_hh, xproj, bt0, sA, sB);
      __threadfence();
      __syncthreads();
      if (threadIdx.x == 0)
        __hip_atomic_store(&flags[idx], 1, __ATOMIC_RELEASE, __HIP_MEMORY_SCOPE_AGENT);
    }
    return;
  }

  // -------- consumer: LSTM scan, one wave per batch element --------
  if (threadIdx.x >= 64) return;
  __builtin_amdgcn_s_setprio(3);
  const int b = bid;
  const int l = threadIdx.x;

  // packed K-pair weights: wA[j] = (W_hh[l][2j], W_hh[l][2j+1]); wB row l+64
  float2 wA[16], wB[16];
#pragma unroll
  for (int j = 0; j < 16; j += 2) {
    float4 v0 = *(const float4*)&W_hh[l * HID + 2 * j];
    wA[j]     = make_float2(v0.x, v0.y);
    wA[j + 1] = make_float2(v0.z, v0.w);
    float4 v1 = *(const float4*)&W_hh[(l + 64) * HID + 2 * j];
    wB[j]     = make_float2(v1.x, v1.y);
    wB[j + 1] = make_float2(v1.z, v1.w);
  }
  // folded activation constants: lanes<32 compute tanh via 2*sig(2x)-1 with
  // the 2x folded into the exp2 multiplier (exact: constant is 2*K)
  const float eB  = (l < HID) ? -2.88539008f : -1.44269504f;
  const float mBc = (l < HID) ? 2.f : 1.f;
  const float aBc = (l < HID) ? -1.f : 0.f;

  float c = 0.f, h = 0.f;
  u64 hp[16];
#pragma unroll
  for (int k = 0; k < 16; ++k) hp[k] = 0ull;

  const float* xb = xproj + (size_t)b * T_LEN * G4;

  auto step = [&](float xa, float xg) {
    // 4 independent chains of depth 4 per gate
    float2 aA[4], aB[4];
    aA[0] = make_float2(xa, 0.f);
    aB[0] = make_float2(xg, 0.f);
#pragma unroll
    for (int q = 1; q < 4; ++q) {
      aA[q] = make_float2(0.f, 0.f);
      aB[q] = make_float2(0.f, 0.f);
    }
#pragma unroll
    for (int j = 0; j < 16; j += 4) {
#pragma unroll
      for (int q = 0; q < 4; ++q) {
        pkfma2(aA[q], wA[j + q], hp[j + q]);
        pkfma2(aB[q], wB[j + q], hp[j + q]);
      }
    }
    float2 tA = pkadd(pkadd(aA[0], aA[1]), pkadd(aA[2], aA[3]));
    float2 tB = pkadd(pkadd(aB[0], aB[1]), pkadd(aB[2], aB[3]));
    float accA = tA.x + tA.y;                  // i (l<32) / f (l>=32)
    float accB = tB.x + tB.y;                  // g (l<32) / o (l>=32)
    float actA = __builtin_amdgcn_rcpf(1.f + __builtin_amdgcn_exp2f(-1.44269504f * accA));
    float sB2  = __builtin_amdgcn_rcpf(1.f + __builtin_amdgcn_exp2f(eB * accB));
    float actB = fmaf(mBc, sB2, aBc);          // tanh g (l<32) / o (l>=32)
    float prod = actA * actB;                  // lanes<32: i*g
    // measured semantics: swap(vdst=0, src=prod) -> dst_new[32+k] = prod[k]
    v2i sw = __builtin_amdgcn_permlane32_swap(0, __float_as_int(prod), false, false);
    float pr = __int_as_float(sw[0]);
    c = fmaf(actA, c, pr);                     // lanes>=32: c = f*c + i*g
    // tanh(c) = 2*sig(2c)-1, 2c folded into exp2 constant; h = o*tanh(c)
    float t  = __builtin_amdgcn_rcpf(1.f + __builtin_amdgcn_exp2f(-2.88539008f * c));
    float o2 = actB + actB;                    // off critical path
    h = fmaf(o2, t, -actB);                    // lanes>=32: h = o*tanh(c)
#pragma unroll
    for (int k = 0; k < 16; ++k) {
      unsigned lo = (unsigned)__builtin_amdgcn_readlane(__float_as_int(h), 32 + 2 * k);
      unsigned hi = (unsigned)__builtin_amdgcn_readlane(__float_as_int(h), 33 + 2 * k);
      hp[k] = (u64)lo | ((u64)hi << 32);
    }
  };

  float A0[CH], B0[CH], A1[CH], B1[CH];
#define STEPS(Aa, Bb) do { _Pragma("unroll") \
  for (int i = 0; i < CH; ++i) step(Aa[i], Bb[i]); } while (0)

  for (int ti = 0; ti < TPB; ++ti) {
    if (!nowait) {
      while (__hip_atomic_load(&flags[ti * 64 + b], __ATOMIC_ACQUIRE,
                               __HIP_MEMORY_SCOPE_AGENT) == 0)
        __builtin_amdgcn_s_sleep(2);
    }
    const float* pb = xb + (size_t)ti * TBT * G4 + l;
    // prologue: chunks 0,1 in flight (32 outstanding loads)
    LOAD_CHUNK(A0, B0, pb); pb += CH * G4;
    LOAD_CHUNK(A1, B1, pb); pb += CH * G4;
#pragma unroll 1
    for (int pc = 0; pc < 7; ++pc) {
      WAIT16();                 // chunk 2pc retired (2pc+1 stays in flight)
      STEPS(A0, B0);
      LOAD_CHUNK(A0, B0, pb); pb += CH * G4;   // chunk 2pc+2
      WAIT16();                 // chunk 2pc+1 retired
      STEPS(A1, B1);
      LOAD_CHUNK(A1, B1, pb); pb += CH * G4;   // chunk 2pc+3
    }
    WAIT16();                   // chunk 14 retired (15 in flight)
    STEPS(A0, B0);
    WAIT0();                    // chunk 15 retired
    STEPS(A1, B1);
  }

  // head: logits = relu(h) @ W_out.T + b_out ; log_softmax  (shuffle-only)
  float hf[HID];
#pragma unroll
  for (int k = 0; k < HID; ++k)
    hf[k] = __int_as_float(__builtin_amdgcn_readlane(__float_as_int(h), 32 + k));
  float logit = 0.f;
  if (l < NOUT) {
    logit = b_out[l];
#pragma unroll
    for (int j = 0; j < HID; ++j) logit += fmaxf(hf[j], 0.f) * W_out[l * HID + j];
  }
  float m = -1e30f;
#pragma unroll
  for (int n = 0; n < NOUT; ++n) m = fmaxf(m, __shfl(logit, n));
  float s = 0.f;
#pragma unroll
  for (int n = 0; n < NOUT; ++n)
    s += __builtin_amdgcn_exp2f(1.44269504089f * (__shfl(logit, n) - m));
  if (l < NOUT)
    out[b * NOUT + l] = logit - m - 0.69314718056f * __builtin_amdgcn_logf(s);
}

// ---- fallback standalone GEMM (serial path if ws too small for flags) ----
__global__ __launch_bounds__(256) void xproj_gemm(
    const float* __restrict__ A, const float* __restrict__ W,
    const float* __restrict__ b_ih, const float* __restrict__ b_hh,
    float* __restrict__ C)
{
  __shared__ float sA[TBT * PAD];
  __shared__ float sB[G4 * PAD];
  const int idx = blockIdx.x;
  const int ti = idx >> 6, bb = idx & 63;
  gemm_tile(A, W, b_ih, b_hh, C, bb * T_LEN + ti * TBT, sA, sB);
}

extern "C" void kernel_launch(void* const* d_in, const int* in_sizes, int n_in,
                              void* d_out, int out_size, void* d_ws, size_t ws_size,
                              hipStream_t stream) {
  const float* specs = (const float*)d_in[0];
  const float* W_ih  = (const float*)d_in[1];
  const float* W_hh  = (const float*)d_in[2];
  const float* b_ih  = (const float*)d_in[3];
  const float* b_hh  = (const float*)d_in[4];
  const float* W_out = (const float*)d_in[5];
  const float* b_out = (const float*)d_in[6];
  float* outp  = (float*)d_out;
  float* xproj = (float*)d_ws;                       // 64 MB
  const size_t xbytes = (size_t)B_SZ * T_LEN * G4 * 4;

  if (ws_size >= xbytes + NTILE * sizeof(int)) {
    int* flags = (int*)((char*)d_ws + xbytes);
    (void)hipMemsetAsync(flags, 0, NTILE * sizeof(int), stream);
    fused<<<NSCAN + NGEMMP, 256, 0, stream>>>(specs, W_ih, b_ih, b_hh, W_hh,
                                              W_out, b_out, outp, xproj, flags, 0);
  } else {
    xproj_gemm<<<NTILE, 256, 0, stream>>>(specs, W_ih, b_ih, b_hh, xproj);
    fused<<<NSCAN, 256, 0, stream>>>(specs, W_ih, b_ih, b_hh, W_hh,
                                     W_out, b_out, outp, xproj, (int*)xproj /*unused*/, 1);
  }
}